// Round 9
// baseline (54.559 us; speedup 1.0000x reference)
//
#include <hip/hip_runtime.h>

// TensorFusion: out = relu(relu(fused @ W1 + b1) @ W2 + b2) @ W3 + b3
// fused[b, i*1024+j*32+k'] = z0[b,i]*z1[b,j]*z2[b,k'], z* = [x*, 1]
// B=256, D=31 (+1 bias -> 32), FUSED=32768, H1=1024, H2=256, NCLS=4
//
// K1: grid = 16 nt x 32 ks = 512 blocks (2/CU), 512 thr (8 waves).
// Block tile M=256 x N=64, K-chunk 1024 (i = ks const -> z0 folded into z2v).
// 32 K-steps (j = step). Staging: thread (n = tid&63, w = tid>>6) loads 4
// scalar dwords (rows 4w..4w+3 of the 32-row step tile, 256B span/wave-instr),
// cvt_pk to f16, 2x ds_write_b32 into [n][36-pad k] tile. Ring of 4 LDS
// buffers + 4 register slots: loads issued 3 STEPS AHEAD (12 outstanding
// loads/wave = 48 KB/CU in flight), LDS written 1 step ahead, counted vmcnt
// left to the compiler, one lgkmcnt(0)+s_barrier per step.

typedef _Float16 half8 __attribute__((ext_vector_type(8)));
typedef _Float16 half4 __attribute__((ext_vector_type(4)));
typedef _Float16 half2 __attribute__((ext_vector_type(2)));
typedef float f32x4 __attribute__((ext_vector_type(4)));
typedef float f32x2 __attribute__((ext_vector_type(2)));

#define KSPLIT 32

// ---------------------------------------------------------------------------
__global__ __launch_bounds__(512, 4) void k1_gemm(
    const float* __restrict__ x0, const float* __restrict__ x1,
    const float* __restrict__ x2, const float* __restrict__ W1,
    _Float16* __restrict__ partial)
{
    __shared__ _Float16 z1L[256 * 36];      // z1[b][j], stride 36 (18 KB)
    __shared__ _Float16 tile[4][64 * 36];   // ring: [n][k 32 + pad 4] (18 KB)

    const int tid  = threadIdx.x;
    const int nt   = blockIdx.x & 15;
    const int ks   = blockIdx.x >> 4;       // = i for this block
    const int lane = tid & 63;
    const int w    = tid >> 6;              // wave 0..7
    const int nl   = lane & 15;
    const int g    = lane >> 4;             // 0..3
    const int mh   = w >> 1;                // M strip: rows [mh*64, +64)
    const int nw   = w & 1;                 // N strip: cols [nw*32, +32)
    const int n0   = nt * 64;

    // ---- z1 table (f16)
    for (int idx = tid; idx < 256 * 32; idx += 512) {
        int b = idx >> 5, j = idx & 31;
        z1L[b * 36 + j] = (_Float16)((j < 31) ? x1[b * 31 + j] : 1.0f);
    }

    // ---- A-side fragments: z2v[ms][e] = z0[b,ks] * z2[b, g*8+e]
    half8 z2v[4];
#pragma unroll
    for (int ms = 0; ms < 4; ++ms) {
        int b = mh * 64 + ms * 16 + nl;
        float v0 = (ks < 31) ? x0[b * 31 + ks] : 1.0f;
#pragma unroll
        for (int e = 0; e < 8; ++e) {
            int kp = g * 8 + e;
            float v2 = (kp < 31) ? x2[b * 31 + kp] : 1.0f;
            z2v[ms][e] = (_Float16)(v0 * v2);
        }
    }

    // ---- staging: thread covers col n = tid&63, rows 4w..4w+3 per step
    const int sn = tid & 63;
    const float* gp = W1 + ((size_t)ks * 1024 + 4 * w) * 1024 + n0 + sn;
    const int woff = sn * 36 + 4 * w;       // f16 idx in tile row sn

    // ---- B-frag read offsets
    const int roff0 = (nw * 32 + nl) * 36 + g * 8;
    const int roff1 = (nw * 32 + 16 + nl) * 36 + g * 8;

    // ---- prologue: issue tiles 0,1,2 into reg slots 0,1,2 (3-deep)
    float rq[4][4];
#pragma unroll
    for (int s = 0; s < 3; ++s) {
#pragma unroll
        for (int q = 0; q < 4; ++q) rq[s][q] = gp[q * 1024];
        gp += 32768;
    }
    {   // write tile 0 -> buf 0 (compiler waits only slot-0's loads)
        half2 h01, h23;
        h01[0] = (_Float16)rq[0][0]; h01[1] = (_Float16)rq[0][1];
        h23[0] = (_Float16)rq[0][2]; h23[1] = (_Float16)rq[0][3];
        *(half2*)&tile[0][woff]     = h01;
        *(half2*)&tile[0][woff + 2] = h23;
    }
    asm volatile("s_waitcnt lgkmcnt(0)\n\ts_barrier" ::: "memory");

    f32x4 acc[4][2] = {};
    half4 z1q[4];

    // STEP(TT): T = t0+TT. compute buf[TT]; issue loads T+3 -> slot (TT+3)&3;
    // write tile T+1 from slot (TT+1)&3 -> buf (TT+1)&3; lgkm+barrier.
#define STEP(TT, ISSUE, WRITE, T0)                                             \
    {                                                                          \
        if (ISSUE) {                                                           \
            _Pragma("unroll")                                                  \
            for (int q = 0; q < 4; ++q) rq[((TT) + 3) & 3][q] = gp[q * 1024];  \
            gp += 32768;                                                       \
        }                                                                      \
        if ((TT) == 0) {                                                       \
            _Pragma("unroll")                                                  \
            for (int ms = 0; ms < 4; ++ms)                                     \
                z1q[ms] = *(const half4*)&z1L[(mh * 64 + ms * 16 + nl) * 36 + (T0)]; \
        }                                                                      \
        const _Float16* tb = &tile[(TT) & 3][0];                               \
        half4 lo0 = *(const half4*)&tb[roff0];                                 \
        half4 hi0 = *(const half4*)&tb[roff0 + 4];                             \
        half4 lo1 = *(const half4*)&tb[roff1];                                 \
        half4 hi1 = *(const half4*)&tb[roff1 + 4];                             \
        half8 bh0 = __builtin_shufflevector(lo0, hi0, 0,1,2,3,4,5,6,7);        \
        half8 bh1 = __builtin_shufflevector(lo1, hi1, 0,1,2,3,4,5,6,7);        \
        _Pragma("unroll")                                                      \
        for (int ms = 0; ms < 4; ++ms) {                                       \
            half8 a = z2v[ms] * z1q[ms][TT];                                   \
            acc[ms][0] = __builtin_amdgcn_mfma_f32_16x16x32_f16(a, bh0, acc[ms][0], 0, 0, 0); \
            acc[ms][1] = __builtin_amdgcn_mfma_f32_16x16x32_f16(a, bh1, acc[ms][1], 0, 0, 0); \
        }                                                                      \
        if (WRITE) {                                                           \
            const float* s = rq[((TT) + 1) & 3];                               \
            half2 h01, h23;                                                    \
            h01[0] = (_Float16)s[0]; h01[1] = (_Float16)s[1];                  \
            h23[0] = (_Float16)s[2]; h23[1] = (_Float16)s[3];                  \
            _Float16* tw = &tile[((TT) + 1) & 3][0];                           \
            *(half2*)&tw[woff]     = h01;                                      \
            *(half2*)&tw[woff + 2] = h23;                                      \
        }                                                                      \
        asm volatile("s_waitcnt lgkmcnt(0)\n\ts_barrier" ::: "memory");        \
    }

    for (int grp = 0; grp < 7; ++grp) {
        const int t0 = grp * 4;
        STEP(0, 1, 1, t0)
        STEP(1, 1, 1, t0)
        STEP(2, 1, 1, t0)
        STEP(3, 1, 1, t0)
    }
    // tail: t = 28..31 (issue tile 31 at t=28; last write at t=30)
    STEP(0, 1, 1, 28)
    STEP(1, 0, 1, 28)
    STEP(2, 0, 1, 28)
    STEP(3, 0, 0, 28)
#undef STEP

    // ---- epilogue: D col = lane&15 (h), row = g*4 + r (b); f16 partials
    _Float16* pbase = partial + ((size_t)ks << 18);
#pragma unroll
    for (int ms = 0; ms < 4; ++ms)
#pragma unroll
        for (int ns = 0; ns < 2; ++ns) {
            int h = n0 + nw * 32 + ns * 16 + nl;
            int b0 = mh * 64 + ms * 16 + g * 4;
#pragma unroll
            for (int r = 0; r < 4; ++r)
                pbase[(b0 + r) * 1024 + h] = (_Float16)acc[ms][ns][r];
        }
}

// ---------------------------------------------------------------------------
// K2: h1[b][h] = relu(sum_ks partial[ks][b][h] + b1[h]); half2 path
// ---------------------------------------------------------------------------
__global__ __launch_bounds__(256) void k2_reduce(
    const _Float16* __restrict__ partial, const float* __restrict__ b1,
    float* __restrict__ h1)
{
    int e2 = blockIdx.x * 256 + threadIdx.x;   // grid 512 -> 131072 pairs
    const half2* pv = (const half2*)partial;
    float s0 = 0.f, s1 = 0.f;
#pragma unroll
    for (int sp = 0; sp < KSPLIT; ++sp) {
        half2 v = pv[(size_t)sp * 131072 + e2];
        s0 += (float)v[0]; s1 += (float)v[1];
    }
    int h = (e2 * 2) & 1023;
    f32x2 o;
    o[0] = fmaxf(s0 + b1[h], 0.f);
    o[1] = fmaxf(s1 + b1[h + 1], 0.f);
    *(f32x2*)&h1[e2 * 2] = o;
}

// ---------------------------------------------------------------------------
// K3: layer 2 partials, M=256 K=1024 N=256; Mtile=32 Ntile=64 Ksplit=8
// ---------------------------------------------------------------------------
__global__ __launch_bounds__(256) void k3_layer2(
    const float* __restrict__ h1, const float* __restrict__ W2,
    float* __restrict__ p2)
{
    __shared__ float h1t[32 * 129];
    __shared__ float w2t[128 * 65];
    const int tid = threadIdx.x;
    const int m0 = blockIdx.x * 32, n0 = blockIdx.y * 64, k0 = blockIdx.z * 128;

    for (int idx = tid; idx < 32 * 128; idx += 256) {
        int m = idx >> 7, kk = idx & 127;
        h1t[m * 129 + kk] = h1[(m0 + m) * 1024 + k0 + kk];
    }
    for (int idx = tid; idx < 128 * 64; idx += 256) {
        int kk = idx >> 6, n = idx & 63;
        w2t[kk * 65 + n] = W2[(k0 + kk) * 256 + n0 + n];
    }
    __syncthreads();

    const int tn = tid & 63, tm = tid >> 6;   // tm 0..3
    float acc[8] = {};
    for (int kk = 0; kk < 128; ++kk) {
        float wv = w2t[kk * 65 + tn];
#pragma unroll
        for (int r = 0; r < 8; ++r)
            acc[r] += h1t[(tm * 8 + r) * 129 + kk] * wv;
    }
#pragma unroll
    for (int r = 0; r < 8; ++r)
        p2[blockIdx.z * 65536 + (m0 + tm * 8 + r) * 256 + n0 + tn] = acc[r];
}

// ---------------------------------------------------------------------------
// K4: h2 = relu(sum_s p2[s] + b2); out = h2 @ W3 + b3. One block per sample.
// ---------------------------------------------------------------------------
__global__ __launch_bounds__(256) void k4_final(
    const float* __restrict__ p2, const float* __restrict__ b2,
    const float* __restrict__ W3, const float* __restrict__ b3,
    float* __restrict__ out)
{
    __shared__ float pL[256 * 5];
    const int b = blockIdx.x, n = threadIdx.x;
    float s = 0.f;
#pragma unroll
    for (int sp = 0; sp < 8; ++sp) s += p2[sp * 65536 + b * 256 + n];
    float h2 = fmaxf(s + b2[n], 0.f);
#pragma unroll
    for (int ccls = 0; ccls < 4; ++ccls) pL[n * 5 + ccls] = h2 * W3[n * 4 + ccls];
    __syncthreads();

    const int lane = n & 63, w = n >> 6;      // wave w handles class c=w
    float v = pL[lane * 5 + w] + pL[(lane + 64) * 5 + w] +
              pL[(lane + 128) * 5 + w] + pL[(lane + 192) * 5 + w];
#pragma unroll
    for (int off = 32; off > 0; off >>= 1) v += __shfl_down(v, off);
    if (lane == 0) out[b * 4 + w] = v + b3[w];
}

extern "C" void kernel_launch(void* const* d_in, const int* in_sizes, int n_in,
                              void* d_out, int out_size, void* d_ws, size_t ws_size,
                              hipStream_t stream)
{
    (void)in_sizes; (void)n_in; (void)out_size; (void)ws_size;
    const float* x0 = (const float*)d_in[0];
    const float* x1 = (const float*)d_in[1];
    const float* x2 = (const float*)d_in[2];
    const float* W1 = (const float*)d_in[3];
    const float* b1 = (const float*)d_in[4];
    const float* W2 = (const float*)d_in[5];
    const float* b2 = (const float*)d_in[6];
    const float* W3 = (const float*)d_in[7];
    const float* b3 = (const float*)d_in[8];
    float* out = (float*)d_out;

    // ws layout: partial f16 [32][256][1024] = 16.78 MB; h1 f32 1 MB; p2 2 MB
    _Float16* partial = (_Float16*)d_ws;
    float* h1 = (float*)((char*)d_ws + (size_t)KSPLIT * 262144 * 2);
    float* p2 = h1 + 262144;

    k1_gemm  <<<dim3(512),     dim3(512), 0, stream>>>(x0, x1, x2, W1, partial);
    k2_reduce<<<dim3(512),     dim3(256), 0, stream>>>(partial, b1, h1);
    k3_layer2<<<dim3(8, 4, 8), dim3(256), 0, stream>>>(h1, W2, p2);
    k4_final <<<dim3(256),     dim3(256), 0, stream>>>(p2, b2, W3, b3, out);
}